// Round 4
// baseline (121.795 us; speedup 1.0000x reference)
//
#include <hip/hip_runtime.h>

typedef __attribute__((ext_vector_type(8))) short bf16x8;
typedef __attribute__((ext_vector_type(4))) float f32x4;
typedef __attribute__((ext_vector_type(16))) float f32x16;

__device__ __forceinline__ ushort f2bf(float f) {
    union { float f; unsigned u; } x; x.f = f;
    unsigned r = x.u + 0x7fffu + ((x.u >> 16) & 1u);
    return (ushort)(r >> 16);
}

__device__ __forceinline__ void async16(const void* g, void* l) {
    __builtin_amdgcn_global_load_lds(
        (const __attribute__((address_space(1))) void*)g,
        (__attribute__((address_space(3))) void*)l, 16, 0, 0);
}

__device__ __forceinline__ f32x4 mfma16(bf16x8 a, bf16x8 b, f32x4 c) {
    return __builtin_amdgcn_mfma_f32_16x16x32_bf16(a, b, c, 0, 0, 0);
}
__device__ __forceinline__ f32x16 mfma32(bf16x8 a, bf16x8 b, f32x16 c) {
    return __builtin_amdgcn_mfma_f32_32x32x16_bf16(a, b, c, 0, 0, 0);
}

__device__ __forceinline__ f32x4 zero4() { f32x4 z = {0.f, 0.f, 0.f, 0.f}; return z; }

// -------- fused fp32 -> bf16 conversion for all 7 tensors, one launch --------
__global__ void cvt7_kernel(
    const float* __restrict__ s0, const float* __restrict__ s1, const float* __restrict__ s2,
    const float* __restrict__ s3, const float* __restrict__ s4, const float* __restrict__ s5,
    const float* __restrict__ s6,
    ushort* __restrict__ d0, ushort* __restrict__ d1, ushort* __restrict__ d2,
    ushort* __restrict__ d3, ushort* __restrict__ d4, ushort* __restrict__ d5,
    ushort* __restrict__ d6)
{
    int y = blockIdx.y;
    const float* s; ushort* d; int n4;
    if      (y == 0) { s = s0; d = d0; n4 = 1048576; }
    else if (y == 1) { s = s1; d = d1; n4 = 1048576; }
    else if (y == 2) { s = s2; d = d2; n4 = 1048576; }
    else if (y == 3) { s = s3; d = d3; n4 = 262144; }
    else if (y == 4) { s = s4; d = d4; n4 = 262144; }
    else if (y == 5) { s = s5; d = d5; n4 = 262144; }
    else             { s = s6; d = d6; n4 = 262144; }
    int i = blockIdx.x * 256 + threadIdx.x;
    if (i >= n4) return;
    float4 v = ((const float4*)s)[i];
    ushort4 o;
    o.x = f2bf(v.x); o.y = f2bf(v.y); o.z = f2bf(v.z); o.w = f2bf(v.w);
    ((ushort4*)d)[i] = o;
}

// -------- shared GEMM core: 128x128 tile, BK in {64,32}, double-buffered --------
// SWAP=false: acc = A-rows x W-rows.  SWAP=true: transposed (W-rows x A-rows).
template<bool SWAP, int BK>
__device__ __forceinline__ void gemm_core(
    const ushort* __restrict__ A, const ushort* __restrict__ W,
    char* smem, int bm, int bn, int tid, f32x4 acc[4][4])
{
    constexpr int TILEB = 128 * BK * 2;            // bytes per matrix per buf
    constexpr int NSTEP = 1024 / BK;
    const int lane = tid & 63;
    const int wid  = tid >> 6;
    const int wr = wid >> 1, wc = wid & 1;
    const int l15 = lane & 15, g = lane >> 4;

    auto stage = [&](int kt, int b) {
        char* As = smem + b * (2 * TILEB);
        char* Bs = As + TILEB;
        if (BK == 64) {
            #pragma unroll
            for (int it = 0; it < 4; ++it) {
                int c = it * 256 + tid;
                int row = c >> 3, inner = c & 7;
                int srcoff = (inner ^ (row & 7)) * 16;
                async16((const char*)A + (size_t)(bm * 128 + row) * 2048 + kt * 128 + srcoff, As + c * 16);
                async16((const char*)W + (size_t)(bn * 128 + row) * 2048 + kt * 128 + srcoff, Bs + c * 16);
            }
        } else {
            #pragma unroll
            for (int it = 0; it < 2; ++it) {
                int c = it * 256 + tid;
                int row = c >> 2, inner = c & 3;
                int srcoff = (inner ^ (row & 3)) * 16;
                async16((const char*)A + (size_t)(bm * 128 + row) * 2048 + kt * 64 + srcoff, As + c * 16);
                async16((const char*)W + (size_t)(bn * 128 + row) * 2048 + kt * 64 + srcoff, Bs + c * 16);
            }
        }
    };

    stage(0, 0);
    __syncthreads();

    for (int kt = 0; kt < NSTEP; ++kt) {
        const int cur = kt & 1;
        if (kt < NSTEP - 1) stage(kt + 1, cur ^ 1);

        const char* As = smem + cur * (2 * TILEB);
        const char* Bs = As + TILEB;
        constexpr int KS = BK / 32;
        bf16x8 af[4][KS], bfr[4][KS];
        #pragma unroll
        for (int mt = 0; mt < 4; ++mt)
            #pragma unroll
            for (int ks = 0; ks < KS; ++ks) {
                int row = wr * 64 + mt * 16 + l15;
                int byte;
                if (BK == 64) byte = (row * 128 + ks * 64 + g * 16) ^ ((row & 7) << 4);
                else          byte = (row * 64 + g * 16) ^ ((row & 3) << 4);
                af[mt][ks] = *(const bf16x8*)(As + byte);
            }
        #pragma unroll
        for (int nt = 0; nt < 4; ++nt)
            #pragma unroll
            for (int ks = 0; ks < KS; ++ks) {
                int row = wc * 64 + nt * 16 + l15;
                int byte;
                if (BK == 64) byte = (row * 128 + ks * 64 + g * 16) ^ ((row & 7) << 4);
                else          byte = (row * 64 + g * 16) ^ ((row & 3) << 4);
                bfr[nt][ks] = *(const bf16x8*)(Bs + byte);
            }
        #pragma unroll
        for (int mt = 0; mt < 4; ++mt)
            #pragma unroll
            for (int nt = 0; nt < 4; ++nt)
                #pragma unroll
                for (int ks = 0; ks < KS; ++ks) {
                    if (SWAP) acc[mt][nt] = mfma16(bfr[nt][ks], af[mt][ks], acc[mt][nt]);
                    else      acc[mt][nt] = mfma16(af[mt][ks], bfr[nt][ks], acc[mt][nt]);
                }
        __syncthreads();
    }
}

// -------- merged QKV projection: grid (96, 8), z = x%3, BK=32 (3 blocks/CU) --------
__global__ __launch_bounds__(256) void gemm_qkv(
    const ushort* __restrict__ Qb, const ushort* __restrict__ Kb, const ushort* __restrict__ Vb,
    const ushort* __restrict__ WQ, const ushort* __restrict__ WK, const ushort* __restrict__ WV,
    ushort* __restrict__ qhb, ushort* __restrict__ khb, ushort* __restrict__ vhT)
{
    __shared__ __align__(16) char smem[32768];
    const int tid = threadIdx.x;
    const int z  = blockIdx.x % 3;
    const int bm = blockIdx.x / 3;
    const int bn = blockIdx.y;
    const int lane = tid & 63;
    const int wid  = tid >> 6;
    const int wr = wid >> 1, wc = wid & 1;
    const int l15 = lane & 15, g = lane >> 4;

    const ushort* A  = (z == 0) ? Qb : (z == 1) ? Kb : Vb;
    const ushort* Wm = (z == 0) ? WQ : (z == 1) ? WK : WV;

    f32x4 acc[4][4];
    #pragma unroll
    for (int i = 0; i < 4; ++i)
        #pragma unroll
        for (int j = 0; j < 4; ++j) acc[i][j] = zero4();

    if (z == 2) {
        gemm_core<true, 32>(A, Wm, smem, bm, bn, tid, acc);
        #pragma unroll
        for (int mt = 0; mt < 4; ++mt)
            #pragma unroll
            for (int nt = 0; nt < 4; ++nt)
                #pragma unroll
                for (int j = 0; j < 4; ++j) {
                    int n = bn * 128 + wc * 64 + nt * 16 + g * 4 + j;
                    int m = bm * 128 + wr * 64 + mt * 16 + l15;
                    int b = m >> 11, s = m & 2047, h = (n >> 6) & 15, d = n & 63;
                    vhT[(((size_t)(b * 16 + h)) * 64 + d) * 2048 + s] = f2bf(acc[mt][nt][j]);
                }
    } else {
        gemm_core<false, 32>(A, Wm, smem, bm, bn, tid, acc);
        const float scale = (z == 0) ? 0.125f : 1.0f;
        ushort* outb = (z == 0) ? qhb : khb;
        #pragma unroll
        for (int mt = 0; mt < 4; ++mt)
            #pragma unroll
            for (int nt = 0; nt < 4; ++nt)
                #pragma unroll
                for (int j = 0; j < 4; ++j) {
                    int m = bm * 128 + wr * 64 + mt * 16 + g * 4 + j;
                    int n = bn * 128 + wc * 64 + nt * 16 + l15;
                    int b = m >> 11, s = m & 2047, h = n >> 6, d = n & 63;
                    outb[(((size_t)(b * 16 + h)) * 2048 + s) * 64 + d] = f2bf(acc[mt][nt][j] * scale);
                }
    }
}

// -------- final GEMM: out = A @ W^T + bias (fp32 out), BK=64 --------
__global__ __launch_bounds__(256) void gemm_fc(
    const ushort* __restrict__ A, const ushort* __restrict__ W,
    float* __restrict__ outf, const float* __restrict__ bias)
{
    __shared__ __align__(16) char smem[65536];
    const int tid = threadIdx.x;
    const int lane = tid & 63;
    const int wid  = tid >> 6;
    const int wr = wid >> 1, wc = wid & 1;
    const int l15 = lane & 15, g = lane >> 4;

    f32x4 acc[4][4];
    #pragma unroll
    for (int i = 0; i < 4; ++i)
        #pragma unroll
        for (int j = 0; j < 4; ++j) acc[i][j] = zero4();

    gemm_core<false, 64>(A, W, smem, blockIdx.x, blockIdx.y, tid, acc);

    #pragma unroll
    for (int mt = 0; mt < 4; ++mt)
        #pragma unroll
        for (int nt = 0; nt < 4; ++nt)
            #pragma unroll
            for (int j = 0; j < 4; ++j) {
                int m = blockIdx.x * 128 + wr * 64 + mt * 16 + g * 4 + j;
                int n = blockIdx.y * 128 + wc * 64 + nt * 16 + l15;
                outf[(size_t)m * 1024 + n] = acc[mt][nt][j] + bias[n];
            }
}

// -------- causal flash attention, KV split across wave-groups --------
// grid (16, 32). block 512 = 8 waves. q-tile 128, KV chunk 128/iter.
// Waves 0-3: even 64-half (q rows wq*32). Waves 4-7: odd 64-half (same q rows).
// End: split-K-style exp-weighted merge of (o, m, l) via LDS.
__global__ __launch_bounds__(512, 4) void attn_kernel(
    const ushort* __restrict__ qh, const ushort* __restrict__ kh,
    const ushort* __restrict__ vhT, ushort* __restrict__ yb)
{
    __shared__ __align__(16) char smem[65536];
    // K: 2 x 16KB @0 (128 rows x 128B, slot^=(row&7)); V^T: 2 x 16KB @32768 (64 rows x 256B, slot^=(row&15))
    const int tid = threadIdx.x;
    const int lane = tid & 63, wid = tid >> 6;
    const int l31 = lane & 31;
    const int hi  = lane >> 5;
    const int group = wid >> 2;          // 0 = even 64-half, 1 = odd
    const int wq    = wid & 3;           // q sub-tile
    const int subkv = group * 64;
    const int bh = blockIdx.y;
    const int qt = (bh < 16) ? (int)blockIdx.x : 15 - (int)blockIdx.x;
    const size_t base = (size_t)bh * 2048 * 64;
    const int qrw = qt * 128 + wq * 32;

    auto stageK = [&](int t, int b) {
        char* Ks = smem + b * 16384;
        #pragma unroll
        for (int it = 0; it < 2; ++it) {
            int c = it * 512 + tid;
            int row = c >> 3, inner = c & 7;
            async16((const char*)kh + (base + (size_t)(t * 128 + row) * 64) * 2 + ((inner ^ (row & 7)) * 16),
                    Ks + c * 16);
        }
    };
    auto stageV = [&](int t, int b) {
        char* Vs = smem + 32768 + b * 16384;
        #pragma unroll
        for (int it = 0; it < 2; ++it) {
            int c = it * 512 + tid;
            int row = c >> 4, inner = c & 15;   // row = d, 16 chunks per 256B row
            async16((const char*)vhT + (base + (size_t)row * 2048 + (size_t)t * 128) * 2 + ((inner ^ (row & 15)) * 16),
                    Vs + c * 16);
        }
    };

    // hoist Q fragments: lane holds Q[qrw + l31][ks*16 + hi*8 + 0..7] (pre-scaled 1/8)
    bf16x8 qf[4];
    #pragma unroll
    for (int ks = 0; ks < 4; ++ks)
        qf[ks] = *(const bf16x8*)((const char*)qh + (base + (size_t)(qrw + l31) * 64) * 2 + ks * 32 + hi * 16);

    f32x16 o[2];
    #pragma unroll
    for (int r = 0; r < 16; ++r) { o[0][r] = 0.f; o[1][r] = 0.f; }
    float m_run = -1e30f, l_run = 0.f;

    stageK(0, 0); stageV(0, 0);
    __syncthreads();

    for (int i = 0; i <= qt; ++i) {
        const int cur = i & 1;
        if (i < qt) { stageK(i + 1, cur ^ 1); stageV(i + 1, cur ^ 1); }

        const int kv0 = i * 128 + subkv;
        if (kv0 <= qrw + 31) {
            const char* Ks = smem + cur * 16384;
            const char* Vs = smem + 32768 + cur * 16384;

            // ---- QK^T (swapped): st[tt][r] over K rows subkv + tt*32 + l31
            f32x16 st[2];
            #pragma unroll
            for (int r = 0; r < 16; ++r) { st[0][r] = 0.f; st[1][r] = 0.f; }
            __builtin_amdgcn_s_setprio(1);
            #pragma unroll
            for (int tt = 0; tt < 2; ++tt)
                #pragma unroll
                for (int ks = 0; ks < 4; ++ks) {
                    int krow = subkv + tt * 32 + l31;
                    int byte = (krow * 128 + ks * 32 + hi * 16) ^ ((krow & 7) << 4);
                    bf16x8 kf = *(const bf16x8*)(Ks + byte);
                    st[tt] = mfma32(kf, qf[ks], st[tt]);
                }
            __builtin_amdgcn_s_setprio(0);

            // ---- causal mask (diagonal tiles only)
            if (kv0 + 63 > qrw) {
                #pragma unroll
                for (int tt = 0; tt < 2; ++tt)
                    #pragma unroll
                    for (int r = 0; r < 16; ++r) {
                        int kv = kv0 + tt * 32 + (r & 3) + 8 * (r >> 2) + 4 * hi;
                        if (kv > qrw + l31) st[tt][r] = -1e30f;
                    }
            }

            // ---- row max (lane-local + cross-half)
            float mx = st[0][0];
            #pragma unroll
            for (int tt = 0; tt < 2; ++tt)
                #pragma unroll
                for (int r = 0; r < 16; ++r) mx = fmaxf(mx, st[tt][r]);
            mx = fmaxf(mx, __shfl_xor(mx, 32));

            // ---- defer-max online softmax (T13, THR=8)
            if (!__all(mx - m_run <= 8.0f)) {
                float mn = fmaxf(m_run, mx);
                float corr = __expf(m_run - mn);
                l_run *= corr;
                m_run = mn;
                #pragma unroll
                for (int r = 0; r < 16; ++r) {
                    int qsrc = (r & 3) + 8 * (r >> 2) + 4 * hi;
                    float c2 = __shfl(corr, qsrc);
                    o[0][r] *= c2; o[1][r] *= c2;
                }
            }

            float sum = 0.f;
            #pragma unroll
            for (int tt = 0; tt < 2; ++tt)
                #pragma unroll
                for (int r = 0; r < 16; ++r) {
                    float p = __expf(st[tt][r] - m_run);
                    st[tt][r] = p;
                    sum += p;
                }
            sum += __shfl_xor(sum, 32);
            l_run += sum;

            // ---- pack P to bf16; exchange across halves
            unsigned Wd[2][8], Xw[2][8];
            #pragma unroll
            for (int tt = 0; tt < 2; ++tt)
                #pragma unroll
                for (int k = 0; k < 8; ++k) {
                    unsigned w;
                    asm("v_cvt_pk_bf16_f32 %0, %1, %2" : "=v"(w) : "v"(st[tt][2 * k]), "v"(st[tt][2 * k + 1]));
                    Wd[tt][k] = w;
                }
            #pragma unroll
            for (int tt = 0; tt < 2; ++tt)
                #pragma unroll
                for (int k = 0; k < 8; ++k)
                    Xw[tt][k] = __shfl_xor((int)Wd[tt][k], 32);

            // ---- PV
            #pragma unroll
            for (int ks = 0; ks < 4; ++ks) {
                const int t2 = ks >> 1, bse = (ks & 1) * 4;
                unsigned w0 = hi ? Xw[t2][bse + 2] : Wd[t2][bse + 0];
                unsigned w1 = hi ? Xw[t2][bse + 3] : Wd[t2][bse + 1];
                unsigned w2 = hi ? Wd[t2][bse + 2] : Xw[t2][bse + 0];
                unsigned w3 = hi ? Wd[t2][bse + 3] : Xw[t2][bse + 1];
                unsigned pw[4] = {w0, w1, w2, w3};
                bf16x8 pf = *(const bf16x8*)pw;
                __builtin_amdgcn_s_setprio(1);
                #pragma unroll
                for (int dt = 0; dt < 2; ++dt) {
                    int vrow = dt * 32 + l31;
                    int colB = subkv * 2 + ks * 32 + hi * 16;
                    int byte = vrow * 256 + (colB ^ ((vrow & 15) << 4));
                    bf16x8 vf = *(const bf16x8*)(Vs + byte);
                    o[dt] = mfma32(pf, vf, o[dt]);
                }
                __builtin_amdgcn_s_setprio(0);
            }
        }
        __syncthreads();
    }

    // ---- merge the two KV halves (split-K style), then store
    float* oml = (float*)smem;           // per wq: [64 lanes][36 floats] (32 o + m + l, pad 2)
    if (group == 1) {
        float* p = oml + (size_t)(wq * 64 + lane) * 36;
        #pragma unroll
        for (int r = 0; r < 16; ++r) { p[r] = o[0][r]; p[16 + r] = o[1][r]; }
        p[32] = m_run; p[33] = l_run;
    }
    __syncthreads();
    if (group == 0) {
        const float* p = oml + (size_t)(wq * 64 + lane) * 36;
        float m1 = p[32], l1 = p[33];
        float mn = fmaxf(m_run, m1);
        float a0 = __expf(m_run - mn);
        float a1 = __expf(m1 - mn);
        float lt = l_run * a0 + l1 * a1;
        float invl = 1.0f / lt;

        const int b = bh >> 4, h = bh & 15;
        #pragma unroll
        for (int r = 0; r < 16; ++r) {
            int qsrc = (r & 3) + 8 * (r >> 2) + 4 * hi;
            float f0 = __shfl(a0, qsrc);
            float f1 = __shfl(a1, qsrc);
            float iv = __shfl(invl, qsrc);
            float v0 = (o[0][r] * f0 + p[r] * f1) * iv;
            float v1 = (o[1][r] * f0 + p[16 + r] * f1) * iv;
            int q = qrw + qsrc;
            size_t rowoff = ((size_t)(b * 2048 + q)) * 1024 + h * 64;
            yb[rowoff + l31]      = f2bf(v0);
            yb[rowoff + 32 + l31] = f2bf(v1);
        }
    }
}

extern "C" void kernel_launch(void* const* d_in, const int* in_sizes, int n_in,
                              void* d_out, int out_size, void* d_ws, size_t ws_size,
                              hipStream_t stream)
{
    const size_t MD = 4096ull * 1024;
    const size_t WD = 1024ull * 1024;
    ushort* ws  = (ushort*)d_ws;
    ushort* Qb  = ws;
    ushort* Kb  = Qb + MD;
    ushort* Vb  = Kb + MD;
    ushort* qhb = Vb + MD;
    ushort* khb = qhb + MD;
    ushort* vhT = khb + MD;
    ushort* WQb = vhT + MD;
    ushort* WKb = WQb + WD;
    ushort* WVb = WKb + WD;
    ushort* Wfb = WVb + WD;
    ushort* yb  = Qb;   // alias: Qb dead after QKV projection

    cvt7_kernel<<<dim3(4096, 7), 256, 0, stream>>>(
        (const float*)d_in[0], (const float*)d_in[1], (const float*)d_in[2],
        (const float*)d_in[3], (const float*)d_in[4], (const float*)d_in[5],
        (const float*)d_in[6],
        Qb, Kb, Vb, WQb, WKb, WVb, Wfb);

    gemm_qkv<<<dim3(96, 8), 256, 0, stream>>>(Qb, Kb, Vb, WQb, WKb, WVb, qhb, khb, vhT);
    attn_kernel<<<dim3(16, 32), 512, 0, stream>>>(qhb, khb, vhT, yb);
    gemm_fc<<<dim3(32, 8), 256, 0, stream>>>(yb, Wfb, (float*)d_out, (const float*)d_in[7]);
}

// Round 5
// 116.960 us; speedup vs baseline: 1.0413x; 1.0413x over previous
//
#include <hip/hip_runtime.h>

typedef __attribute__((ext_vector_type(8))) short bf16x8;
typedef __attribute__((ext_vector_type(4))) float f32x4;
typedef __attribute__((ext_vector_type(16))) float f32x16;

__device__ __forceinline__ ushort f2bf(float f) {
    union { float f; unsigned u; } x; x.f = f;
    unsigned r = x.u + 0x7fffu + ((x.u >> 16) & 1u);
    return (ushort)(r >> 16);
}

__device__ __forceinline__ void async16(const void* g, void* l) {
    __builtin_amdgcn_global_load_lds(
        (const __attribute__((address_space(1))) void*)g,
        (__attribute__((address_space(3))) void*)l, 16, 0, 0);
}

__device__ __forceinline__ f32x4 mfma16(bf16x8 a, bf16x8 b, f32x4 c) {
    return __builtin_amdgcn_mfma_f32_16x16x32_bf16(a, b, c, 0, 0, 0);
}
__device__ __forceinline__ f32x16 mfma32(bf16x8 a, bf16x8 b, f32x16 c) {
    return __builtin_amdgcn_mfma_f32_32x32x16_bf16(a, b, c, 0, 0, 0);
}

__device__ __forceinline__ f32x4 zero4() { f32x4 z = {0.f, 0.f, 0.f, 0.f}; return z; }

// counted-vmcnt barrier: ensure current tile's staging landed (N = loads still
// allowed in flight), drain own LDS reads, then raw barrier. sched_barrier
// fences per rule #18 (prevent hoisting next-tile ds_reads above the wait).
#define PIPE_BARRIER(cond_more)                                          \
    do {                                                                 \
        if (cond_more) asm volatile("s_waitcnt vmcnt(4)" ::: "memory");  \
        else           asm volatile("s_waitcnt vmcnt(0)" ::: "memory");  \
        asm volatile("s_waitcnt lgkmcnt(0)" ::: "memory");               \
        __builtin_amdgcn_sched_barrier(0);                               \
        __builtin_amdgcn_s_barrier();                                    \
        __builtin_amdgcn_sched_barrier(0);                               \
    } while (0)

// -------- fused fp32 -> bf16 conversion for all 7 tensors, one launch --------
__global__ void cvt7_kernel(
    const float* __restrict__ s0, const float* __restrict__ s1, const float* __restrict__ s2,
    const float* __restrict__ s3, const float* __restrict__ s4, const float* __restrict__ s5,
    const float* __restrict__ s6,
    ushort* __restrict__ d0, ushort* __restrict__ d1, ushort* __restrict__ d2,
    ushort* __restrict__ d3, ushort* __restrict__ d4, ushort* __restrict__ d5,
    ushort* __restrict__ d6)
{
    int y = blockIdx.y;
    const float* s; ushort* d; int n4;
    if      (y == 0) { s = s0; d = d0; n4 = 1048576; }
    else if (y == 1) { s = s1; d = d1; n4 = 1048576; }
    else if (y == 2) { s = s2; d = d2; n4 = 1048576; }
    else if (y == 3) { s = s3; d = d3; n4 = 262144; }
    else if (y == 4) { s = s4; d = d4; n4 = 262144; }
    else if (y == 5) { s = s5; d = d5; n4 = 262144; }
    else             { s = s6; d = d6; n4 = 262144; }
    int i = blockIdx.x * 256 + threadIdx.x;
    if (i >= n4) return;
    float4 v = ((const float4*)s)[i];
    ushort4 o;
    o.x = f2bf(v.x); o.y = f2bf(v.y); o.z = f2bf(v.z); o.w = f2bf(v.w);
    ((ushort4*)d)[i] = o;
}

// -------- shared GEMM core: 128x128 tile, BK=32, 3-deep counted-vmcnt pipeline --------
// LDS: 3 bufs x (A 8KB + B 8KB) = 48KB. Per-wave loads/stage = 4 -> steady vmcnt(4).
template<bool SWAP>
__device__ __forceinline__ void gemm_core(
    const ushort* __restrict__ A, const ushort* __restrict__ W,
    char* smem, int bm, int bn, int tid, f32x4 acc[4][4])
{
    const int lane = tid & 63;
    const int wid  = tid >> 6;
    const int wr = wid >> 1, wc = wid & 1;
    const int l15 = lane & 15, g = lane >> 4;

    auto stage = [&](int kt) {
        char* As = smem + (kt % 3) * 16384;
        char* Bs = As + 8192;
        #pragma unroll
        for (int it = 0; it < 2; ++it) {
            int c = it * 256 + tid;
            int row = c >> 2, inner = c & 3;
            int srcoff = (inner ^ (row & 3)) * 16;
            async16((const char*)A + (size_t)(bm * 128 + row) * 2048 + kt * 64 + srcoff, As + c * 16);
            async16((const char*)W + (size_t)(bn * 128 + row) * 2048 + kt * 64 + srcoff, Bs + c * 16);
        }
    };

    stage(0);
    stage(1);

    for (int kt = 0; kt < 32; ++kt) {
        PIPE_BARRIER(kt < 31);
        if (kt < 30) stage(kt + 2);

        const char* As = smem + (kt % 3) * 16384;
        const char* Bs = As + 8192;
        bf16x8 af[4], bfr[4];
        #pragma unroll
        for (int mt = 0; mt < 4; ++mt) {
            int row = wr * 64 + mt * 16 + l15;
            af[mt] = *(const bf16x8*)(As + ((row * 64 + g * 16) ^ ((row & 3) << 4)));
        }
        #pragma unroll
        for (int nt = 0; nt < 4; ++nt) {
            int row = wc * 64 + nt * 16 + l15;
            bfr[nt] = *(const bf16x8*)(Bs + ((row * 64 + g * 16) ^ ((row & 3) << 4)));
        }
        __builtin_amdgcn_s_setprio(1);
        #pragma unroll
        for (int mt = 0; mt < 4; ++mt)
            #pragma unroll
            for (int nt = 0; nt < 4; ++nt) {
                if (SWAP) acc[mt][nt] = mfma16(bfr[nt], af[mt], acc[mt][nt]);
                else      acc[mt][nt] = mfma16(af[mt], bfr[nt], acc[mt][nt]);
            }
        __builtin_amdgcn_s_setprio(0);
    }
}

// -------- merged QKV projection: grid (96, 8), z = x%3 --------
__global__ __launch_bounds__(256, 2) void gemm_qkv(
    const ushort* __restrict__ Qb, const ushort* __restrict__ Kb, const ushort* __restrict__ Vb,
    const ushort* __restrict__ WQ, const ushort* __restrict__ WK, const ushort* __restrict__ WV,
    ushort* __restrict__ qhb, ushort* __restrict__ khb, ushort* __restrict__ vhT)
{
    __shared__ __align__(16) char smem[49152];
    const int tid = threadIdx.x;
    const int z  = blockIdx.x % 3;
    const int bm = blockIdx.x / 3;
    const int bn = blockIdx.y;
    const int lane = tid & 63;
    const int wid  = tid >> 6;
    const int wr = wid >> 1, wc = wid & 1;
    const int l15 = lane & 15, g = lane >> 4;

    const ushort* A  = (z == 0) ? Qb : (z == 1) ? Kb : Vb;
    const ushort* Wm = (z == 0) ? WQ : (z == 1) ? WK : WV;

    f32x4 acc[4][4];
    #pragma unroll
    for (int i = 0; i < 4; ++i)
        #pragma unroll
        for (int j = 0; j < 4; ++j) acc[i][j] = zero4();

    if (z == 2) {
        gemm_core<true>(A, Wm, smem, bm, bn, tid, acc);
        #pragma unroll
        for (int mt = 0; mt < 4; ++mt)
            #pragma unroll
            for (int nt = 0; nt < 4; ++nt)
                #pragma unroll
                for (int j = 0; j < 4; ++j) {
                    int n = bn * 128 + wc * 64 + nt * 16 + g * 4 + j;
                    int m = bm * 128 + wr * 64 + mt * 16 + l15;
                    int b = m >> 11, s = m & 2047, h = (n >> 6) & 15, d = n & 63;
                    vhT[(((size_t)(b * 16 + h)) * 64 + d) * 2048 + s] = f2bf(acc[mt][nt][j]);
                }
    } else {
        gemm_core<false>(A, Wm, smem, bm, bn, tid, acc);
        const float scale = (z == 0) ? 0.125f : 1.0f;
        ushort* outb = (z == 0) ? qhb : khb;
        #pragma unroll
        for (int mt = 0; mt < 4; ++mt)
            #pragma unroll
            for (int nt = 0; nt < 4; ++nt)
                #pragma unroll
                for (int j = 0; j < 4; ++j) {
                    int m = bm * 128 + wr * 64 + mt * 16 + g * 4 + j;
                    int n = bn * 128 + wc * 64 + nt * 16 + l15;
                    int b = m >> 11, s = m & 2047, h = n >> 6, d = n & 63;
                    outb[(((size_t)(b * 16 + h)) * 2048 + s) * 64 + d] = f2bf(acc[mt][nt][j] * scale);
                }
    }
}

// -------- final GEMM: out = A @ W^T + bias (fp32 out) --------
__global__ __launch_bounds__(256, 2) void gemm_fc(
    const ushort* __restrict__ A, const ushort* __restrict__ W,
    float* __restrict__ outf, const float* __restrict__ bias)
{
    __shared__ __align__(16) char smem[49152];
    const int tid = threadIdx.x;
    const int lane = tid & 63;
    const int wid  = tid >> 6;
    const int wr = wid >> 1, wc = wid & 1;
    const int l15 = lane & 15, g = lane >> 4;

    f32x4 acc[4][4];
    #pragma unroll
    for (int i = 0; i < 4; ++i)
        #pragma unroll
        for (int j = 0; j < 4; ++j) acc[i][j] = zero4();

    gemm_core<false>(A, W, smem, blockIdx.x, blockIdx.y, tid, acc);

    #pragma unroll
    for (int mt = 0; mt < 4; ++mt)
        #pragma unroll
        for (int nt = 0; nt < 4; ++nt)
            #pragma unroll
            for (int j = 0; j < 4; ++j) {
                int m = blockIdx.x * 128 + wr * 64 + mt * 16 + g * 4 + j;
                int n = blockIdx.y * 128 + wc * 64 + nt * 16 + l15;
                outf[(size_t)m * 1024 + n] = acc[mt][nt][j] + bias[n];
            }
}

// -------- causal flash attention, counted-vmcnt 3-deep pipeline --------
// grid (8, 32). block 512 = 8 waves. Each block serially does q-tiles {x, 15-x}
// -> exactly 17 KV-128 iters per block (perfect balance). Waves 0-3: even
// KV-64 half, waves 4-7: odd half; exp-weighted merge per phase.
__global__ __launch_bounds__(512, 2) void attn_kernel(
    const ushort* __restrict__ qh, const ushort* __restrict__ kh,
    const ushort* __restrict__ vhT, ushort* __restrict__ yb)
{
    __shared__ __align__(16) char smem[135168];
    // bufs: 3 x 32KB (K 16KB @ b*32768, V^T 16KB @ b*32768+16384); oml @ 98304
    const int tid = threadIdx.x;
    const int lane = tid & 63, wid = tid >> 6;
    const int l31 = lane & 31;
    const int hi  = lane >> 5;
    const int group = wid >> 2;          // 0 = even KV-64 half, 1 = odd
    const int wq    = wid & 3;
    const int subkv = group * 64;
    const int bh = blockIdx.y;
    const size_t base = (size_t)bh * 2048 * 64;
    const int b_ = bh >> 4, h_ = bh & 15;
    float* oml = (float*)(smem + 98304);

    auto stageK = [&](int t) {
        char* Ks = smem + (t % 3) * 32768;
        #pragma unroll
        for (int it = 0; it < 2; ++it) {
            int c = it * 512 + tid;
            int row = c >> 3, inner = c & 7;
            async16((const char*)kh + (base + (size_t)(t * 128 + row) * 64) * 2 + ((inner ^ (row & 7)) * 16),
                    Ks + c * 16);
        }
    };
    auto stageV = [&](int t) {
        char* Vs = smem + (t % 3) * 32768 + 16384;
        #pragma unroll
        for (int it = 0; it < 2; ++it) {
            int c = it * 512 + tid;
            int row = c >> 4, inner = c & 15;   // row = d
            async16((const char*)vhT + (base + (size_t)row * 2048 + (size_t)t * 128) * 2 + ((inner ^ (row & 15)) * 16),
                    Vs + c * 16);
        }
    };

    for (int p = 0; p < 2; ++p) {
        const int qt  = (p == 0) ? (int)blockIdx.x : 15 - (int)blockIdx.x;
        const int qrw = qt * 128 + wq * 32;

        // hoist Q fragments (pre-scaled by 1/8 at projection)
        bf16x8 qf[4];
        #pragma unroll
        for (int ks = 0; ks < 4; ++ks)
            qf[ks] = *(const bf16x8*)((const char*)qh + (base + (size_t)(qrw + l31) * 64) * 2 + ks * 32 + hi * 16);

        f32x16 o[2];
        #pragma unroll
        for (int r = 0; r < 16; ++r) { o[0][r] = 0.f; o[1][r] = 0.f; }
        float m_run = -1e30f, l_run = 0.f;

        stageK(0); stageV(0);
        if (qt >= 1) { stageK(1); stageV(1); }

        for (int t = 0; t <= qt; ++t) {
            PIPE_BARRIER(t < qt);
            if (t + 2 <= qt) { stageK(t + 2); stageV(t + 2); }

            const int kv0 = t * 128 + subkv;
            if (kv0 <= qrw + 31) {
                const char* Ks = smem + (t % 3) * 32768;
                const char* Vs = Ks + 16384;

                // ---- QK^T (swapped): st[tt][r] over K rows subkv + tt*32 + l31
                f32x16 st[2];
                #pragma unroll
                for (int r = 0; r < 16; ++r) { st[0][r] = 0.f; st[1][r] = 0.f; }
                __builtin_amdgcn_s_setprio(1);
                #pragma unroll
                for (int tt = 0; tt < 2; ++tt)
                    #pragma unroll
                    for (int ks = 0; ks < 4; ++ks) {
                        int krow = subkv + tt * 32 + l31;
                        int byte = (krow * 128 + ks * 32 + hi * 16) ^ ((krow & 7) << 4);
                        bf16x8 kf = *(const bf16x8*)(Ks + byte);
                        st[tt] = mfma32(kf, qf[ks], st[tt]);
                    }
                __builtin_amdgcn_s_setprio(0);

                // ---- causal mask (diagonal tiles only)
                if (kv0 + 63 > qrw) {
                    #pragma unroll
                    for (int tt = 0; tt < 2; ++tt)
                        #pragma unroll
                        for (int r = 0; r < 16; ++r) {
                            int kv = kv0 + tt * 32 + (r & 3) + 8 * (r >> 2) + 4 * hi;
                            if (kv > qrw + l31) st[tt][r] = -1e30f;
                        }
                }

                // ---- row max
                float mx = st[0][0];
                #pragma unroll
                for (int tt = 0; tt < 2; ++tt)
                    #pragma unroll
                    for (int r = 0; r < 16; ++r) mx = fmaxf(mx, st[tt][r]);
                mx = fmaxf(mx, __shfl_xor(mx, 32));

                // ---- defer-max online softmax (T13, THR=8)
                if (!__all(mx - m_run <= 8.0f)) {
                    float mn = fmaxf(m_run, mx);
                    float corr = __expf(m_run - mn);
                    l_run *= corr;
                    m_run = mn;
                    #pragma unroll
                    for (int r = 0; r < 16; ++r) {
                        int qsrc = (r & 3) + 8 * (r >> 2) + 4 * hi;
                        float c2 = __shfl(corr, qsrc);
                        o[0][r] *= c2; o[1][r] *= c2;
                    }
                }

                float sum = 0.f;
                #pragma unroll
                for (int tt = 0; tt < 2; ++tt)
                    #pragma unroll
                    for (int r = 0; r < 16; ++r) {
                        float pw = __expf(st[tt][r] - m_run);
                        st[tt][r] = pw;
                        sum += pw;
                    }
                sum += __shfl_xor(sum, 32);
                l_run += sum;

                // ---- pack P to bf16; exchange across halves
                unsigned Wd[2][8], Xw[2][8];
                #pragma unroll
                for (int tt = 0; tt < 2; ++tt)
                    #pragma unroll
                    for (int k = 0; k < 8; ++k) {
                        unsigned w;
                        asm("v_cvt_pk_bf16_f32 %0, %1, %2" : "=v"(w) : "v"(st[tt][2 * k]), "v"(st[tt][2 * k + 1]));
                        Wd[tt][k] = w;
                    }
                #pragma unroll
                for (int tt = 0; tt < 2; ++tt)
                    #pragma unroll
                    for (int k = 0; k < 8; ++k)
                        Xw[tt][k] = __shfl_xor((int)Wd[tt][k], 32);

                // ---- PV
                #pragma unroll
                for (int ks = 0; ks < 4; ++ks) {
                    const int t2 = ks >> 1, bse = (ks & 1) * 4;
                    unsigned w0 = hi ? Xw[t2][bse + 2] : Wd[t2][bse + 0];
                    unsigned w1 = hi ? Xw[t2][bse + 3] : Wd[t2][bse + 1];
                    unsigned w2 = hi ? Wd[t2][bse + 2] : Xw[t2][bse + 0];
                    unsigned w3 = hi ? Wd[t2][bse + 3] : Xw[t2][bse + 1];
                    unsigned pw4[4] = {w0, w1, w2, w3};
                    bf16x8 pf = *(const bf16x8*)pw4;
                    __builtin_amdgcn_s_setprio(1);
                    #pragma unroll
                    for (int dt = 0; dt < 2; ++dt) {
                        int vrow = dt * 32 + l31;
                        int colB = subkv * 2 + ks * 32 + hi * 16;
                        int byte = vrow * 256 + (colB ^ ((vrow & 15) << 4));
                        bf16x8 vf = *(const bf16x8*)(Vs + byte);
                        o[dt] = mfma32(pf, vf, o[dt]);
                    }
                    __builtin_amdgcn_s_setprio(0);
                }
            }
        }

        // ---- merge the two KV halves, store this phase's q-tile
        __syncthreads();
        if (group == 1) {
            float* pp = oml + (size_t)(wq * 64 + lane) * 36;
            #pragma unroll
            for (int r = 0; r < 16; ++r) { pp[r] = o[0][r]; pp[16 + r] = o[1][r]; }
            pp[32] = m_run; pp[33] = l_run;
        }
        __syncthreads();
        if (group == 0) {
            const float* pp = oml + (size_t)(wq * 64 + lane) * 36;
            float m1 = pp[32], l1 = pp[33];
            float mn = fmaxf(m_run, m1);
            float a0 = __expf(m_run - mn);
            float a1 = __expf(m1 - mn);
            float lt = l_run * a0 + l1 * a1;
            float invl = 1.0f / lt;
            #pragma unroll
            for (int r = 0; r < 16; ++r) {
                int qsrc = (r & 3) + 8 * (r >> 2) + 4 * hi;
                float f0 = __shfl(a0, qsrc);
                float f1 = __shfl(a1, qsrc);
                float iv = __shfl(invl, qsrc);
                float v0 = (o[0][r] * f0 + pp[r] * f1) * iv;
                float v1 = (o[1][r] * f0 + pp[16 + r] * f1) * iv;
                int q = qrw + qsrc;
                size_t rowoff = ((size_t)(b_ * 2048 + q)) * 1024 + h_ * 64;
                yb[rowoff + l31]      = f2bf(v0);
                yb[rowoff + 32 + l31] = f2bf(v1);
            }
        }
        __syncthreads();
    }
}

extern "C" void kernel_launch(void* const* d_in, const int* in_sizes, int n_in,
                              void* d_out, int out_size, void* d_ws, size_t ws_size,
                              hipStream_t stream)
{
    const size_t MD = 4096ull * 1024;
    const size_t WD = 1024ull * 1024;
    ushort* ws  = (ushort*)d_ws;
    ushort* Qb  = ws;
    ushort* Kb  = Qb + MD;
    ushort* Vb  = Kb + MD;
    ushort* qhb = Vb + MD;
    ushort* khb = qhb + MD;
    ushort* vhT = khb + MD;
    ushort* WQb = vhT + MD;
    ushort* WKb = WQb + WD;
    ushort* WVb = WKb + WD;
    ushort* Wfb = WVb + WD;
    ushort* yb  = Qb;   // alias: Qb dead after QKV projection

    cvt7_kernel<<<dim3(4096, 7), 256, 0, stream>>>(
        (const float*)d_in[0], (const float*)d_in[1], (const float*)d_in[2],
        (const float*)d_in[3], (const float*)d_in[4], (const float*)d_in[5],
        (const float*)d_in[6],
        Qb, Kb, Vb, WQb, WKb, WVb, Wfb);

    gemm_qkv<<<dim3(96, 8), 256, 0, stream>>>(Qb, Kb, Vb, WQb, WKb, WVb, qhb, khb, vhT);
    attn_kernel<<<dim3(8, 32), 512, 0, stream>>>(qhb, khb, vhT, yb);
    gemm_fc<<<dim3(32, 8), 256, 0, stream>>>(yb, Wfb, (float*)d_out, (const float*)d_in[7]);
}

// Round 8
// 116.817 us; speedup vs baseline: 1.0426x; 1.0012x over previous
//
#include <hip/hip_runtime.h>

typedef __attribute__((ext_vector_type(8))) short bf16x8;
typedef __attribute__((ext_vector_type(4))) float f32x4;
typedef __attribute__((ext_vector_type(16))) float f32x16;

__device__ __forceinline__ ushort f2bf(float f) {
    union { float f; unsigned u; } x; x.f = f;
    unsigned r = x.u + 0x7fffu + ((x.u >> 16) & 1u);
    return (ushort)(r >> 16);
}

__device__ __forceinline__ void async16(const void* g, void* l) {
    __builtin_amdgcn_global_load_lds(
        (const __attribute__((address_space(1))) void*)g,
        (__attribute__((address_space(3))) void*)l, 16, 0, 0);
}

__device__ __forceinline__ f32x4 mfma16(bf16x8 a, bf16x8 b, f32x4 c) {
    return __builtin_amdgcn_mfma_f32_16x16x32_bf16(a, b, c, 0, 0, 0);
}
__device__ __forceinline__ f32x16 mfma32(bf16x8 a, bf16x8 b, f32x16 c) {
    return __builtin_amdgcn_mfma_f32_32x32x16_bf16(a, b, c, 0, 0, 0);
}

__device__ __forceinline__ f32x4 zero4() { f32x4 z = {0.f, 0.f, 0.f, 0.f}; return z; }

// cross-half (lane vs lane^32) reduce — VERIFIED shfl_xor form (R3-R5).
// NOTE: inline-asm v_permlane32_swap_b32 versions failed correctness in both
// operand orders (R6/R7, absmax ~4) — do not reintroduce without an A/B on
// the __builtin_amdgcn_permlane32_swap builtin.
__device__ __forceinline__ float xhalf_max(float v) {
    return fmaxf(v, __shfl_xor(v, 32));
}
__device__ __forceinline__ float xhalf_sum(float v) {
    return v + __shfl_xor(v, 32);
}

#define PIPE_BARRIER(cond_more)                                          \
    do {                                                                 \
        if (cond_more) asm volatile("s_waitcnt vmcnt(4)" ::: "memory");  \
        else           asm volatile("s_waitcnt vmcnt(0)" ::: "memory");  \
        asm volatile("s_waitcnt lgkmcnt(0)" ::: "memory");               \
        __builtin_amdgcn_sched_barrier(0);                               \
        __builtin_amdgcn_s_barrier();                                    \
        __builtin_amdgcn_sched_barrier(0);                               \
    } while (0)

#define END_BARRIER()                                                    \
    do {                                                                 \
        asm volatile("s_waitcnt lgkmcnt(0)" ::: "memory");               \
        __builtin_amdgcn_sched_barrier(0);                               \
        __builtin_amdgcn_s_barrier();                                    \
        __builtin_amdgcn_sched_barrier(0);                               \
    } while (0)

// -------- fused fp32 -> bf16 conversion for all 7 tensors, one launch --------
__global__ void cvt7_kernel(
    const float* __restrict__ s0, const float* __restrict__ s1, const float* __restrict__ s2,
    const float* __restrict__ s3, const float* __restrict__ s4, const float* __restrict__ s5,
    const float* __restrict__ s6,
    ushort* __restrict__ d0, ushort* __restrict__ d1, ushort* __restrict__ d2,
    ushort* __restrict__ d3, ushort* __restrict__ d4, ushort* __restrict__ d5,
    ushort* __restrict__ d6)
{
    int y = blockIdx.y;
    const float* s; ushort* d; int n4;
    if      (y == 0) { s = s0; d = d0; n4 = 1048576; }
    else if (y == 1) { s = s1; d = d1; n4 = 1048576; }
    else if (y == 2) { s = s2; d = d2; n4 = 1048576; }
    else if (y == 3) { s = s3; d = d3; n4 = 262144; }
    else if (y == 4) { s = s4; d = d4; n4 = 262144; }
    else if (y == 5) { s = s5; d = d5; n4 = 262144; }
    else             { s = s6; d = d6; n4 = 262144; }
    int i = blockIdx.x * 256 + threadIdx.x;
    if (i >= n4) return;
    float4 v = ((const float4*)s)[i];
    ushort4 o;
    o.x = f2bf(v.x); o.y = f2bf(v.y); o.z = f2bf(v.z); o.w = f2bf(v.w);
    ((ushort4*)d)[i] = o;
}

// -------- shared GEMM core: 128x128 tile, BK=32, 3-deep counted-vmcnt pipeline --------
template<bool SWAP>
__device__ __forceinline__ void gemm_core(
    const ushort* __restrict__ A, const ushort* __restrict__ W,
    char* smem, int bm, int bn, int tid, f32x4 acc[4][4])
{
    const int lane = tid & 63;
    const int wid  = tid >> 6;
    const int wr = wid >> 1, wc = wid & 1;
    const int l15 = lane & 15, g = lane >> 4;

    auto stage = [&](int kt) {
        char* As = smem + (kt % 3) * 16384;
        char* Bs = As + 8192;
        #pragma unroll
        for (int it = 0; it < 2; ++it) {
            int c = it * 256 + tid;
            int row = c >> 2, inner = c & 3;
            int srcoff = (inner ^ (row & 3)) * 16;
            async16((const char*)A + (size_t)(bm * 128 + row) * 2048 + kt * 64 + srcoff, As + c * 16);
            async16((const char*)W + (size_t)(bn * 128 + row) * 2048 + kt * 64 + srcoff, Bs + c * 16);
        }
    };

    stage(0);
    stage(1);

    for (int kt = 0; kt < 32; ++kt) {
        PIPE_BARRIER(kt < 31);
        if (kt < 30) stage(kt + 2);

        const char* As = smem + (kt % 3) * 16384;
        const char* Bs = As + 8192;
        bf16x8 af[4], bfr[4];
        #pragma unroll
        for (int mt = 0; mt < 4; ++mt) {
            int row = wr * 64 + mt * 16 + l15;
            af[mt] = *(const bf16x8*)(As + ((row * 64 + g * 16) ^ ((row & 3) << 4)));
        }
        #pragma unroll
        for (int nt = 0; nt < 4; ++nt) {
            int row = wc * 64 + nt * 16 + l15;
            bfr[nt] = *(const bf16x8*)(Bs + ((row * 64 + g * 16) ^ ((row & 3) << 4)));
        }
        __builtin_amdgcn_s_setprio(1);
        #pragma unroll
        for (int mt = 0; mt < 4; ++mt)
            #pragma unroll
            for (int nt = 0; nt < 4; ++nt) {
                if (SWAP) acc[mt][nt] = mfma16(bfr[nt], af[mt], acc[mt][nt]);
                else      acc[mt][nt] = mfma16(af[mt], bfr[nt], acc[mt][nt]);
            }
        __builtin_amdgcn_s_setprio(0);
    }
}

// -------- merged QKV projection: grid (96, 8), z = x%3 --------
// Q scaled by 0.125*log2(e) (exp2-domain softmax downstream).
__global__ __launch_bounds__(256, 2) void gemm_qkv(
    const ushort* __restrict__ Qb, const ushort* __restrict__ Kb, const ushort* __restrict__ Vb,
    const ushort* __restrict__ WQ, const ushort* __restrict__ WK, const ushort* __restrict__ WV,
    ushort* __restrict__ qhb, ushort* __restrict__ khb, ushort* __restrict__ vhT)
{
    __shared__ __align__(16) char smem[49152];
    const int tid = threadIdx.x;
    const int z  = blockIdx.x % 3;
    const int bm = blockIdx.x / 3;
    const int bn = blockIdx.y;
    const int lane = tid & 63;
    const int wid  = tid >> 6;
    const int wr = wid >> 1, wc = wid & 1;
    const int l15 = lane & 15, g = lane >> 4;

    const ushort* A  = (z == 0) ? Qb : (z == 1) ? Kb : Vb;
    const ushort* Wm = (z == 0) ? WQ : (z == 1) ? WK : WV;

    f32x4 acc[4][4];
    #pragma unroll
    for (int i = 0; i < 4; ++i)
        #pragma unroll
        for (int j = 0; j < 4; ++j) acc[i][j] = zero4();

    if (z == 2) {
        gemm_core<true>(A, Wm, smem, bm, bn, tid, acc);
        #pragma unroll
        for (int mt = 0; mt < 4; ++mt)
            #pragma unroll
            for (int nt = 0; nt < 4; ++nt)
                #pragma unroll
                for (int j = 0; j < 4; ++j) {
                    int n = bn * 128 + wc * 64 + nt * 16 + g * 4 + j;
                    int m = bm * 128 + wr * 64 + mt * 16 + l15;
                    int b = m >> 11, s = m & 2047, h = (n >> 6) & 15, d = n & 63;
                    vhT[(((size_t)(b * 16 + h)) * 64 + d) * 2048 + s] = f2bf(acc[mt][nt][j]);
                }
    } else {
        gemm_core<false>(A, Wm, smem, bm, bn, tid, acc);
        const float scale = (z == 0) ? 0.18033688011112042f : 1.0f;  // 0.125 * log2(e)
        ushort* outb = (z == 0) ? qhb : khb;
        #pragma unroll
        for (int mt = 0; mt < 4; ++mt)
            #pragma unroll
            for (int nt = 0; nt < 4; ++nt)
                #pragma unroll
                for (int j = 0; j < 4; ++j) {
                    int m = bm * 128 + wr * 64 + mt * 16 + g * 4 + j;
                    int n = bn * 128 + wc * 64 + nt * 16 + l15;
                    int b = m >> 11, s = m & 2047, h = n >> 6, d = n & 63;
                    outb[(((size_t)(b * 16 + h)) * 2048 + s) * 64 + d] = f2bf(acc[mt][nt][j] * scale);
                }
    }
}

// -------- final GEMM: out = A @ W^T + bias (fp32 out) --------
__global__ __launch_bounds__(256, 2) void gemm_fc(
    const ushort* __restrict__ A, const ushort* __restrict__ W,
    float* __restrict__ outf, const float* __restrict__ bias)
{
    __shared__ __align__(16) char smem[49152];
    const int tid = threadIdx.x;
    const int lane = tid & 63;
    const int wid  = tid >> 6;
    const int wr = wid >> 1, wc = wid & 1;
    const int l15 = lane & 15, g = lane >> 4;

    f32x4 acc[4][4];
    #pragma unroll
    for (int i = 0; i < 4; ++i)
        #pragma unroll
        for (int j = 0; j < 4; ++j) acc[i][j] = zero4();

    gemm_core<false>(A, W, smem, blockIdx.x, blockIdx.y, tid, acc);

    #pragma unroll
    for (int mt = 0; mt < 4; ++mt)
        #pragma unroll
        for (int nt = 0; nt < 4; ++nt)
            #pragma unroll
            for (int j = 0; j < 4; ++j) {
                int m = blockIdx.x * 128 + wr * 64 + mt * 16 + g * 4 + j;
                int n = blockIdx.y * 128 + wc * 64 + nt * 16 + l15;
                outf[(size_t)m * 1024 + n] = acc[mt][nt][j] + bias[n];
            }
}

// -------- causal flash attention --------
// grid 256 1-D. block 512 = 8 waves. XCD-aware decode: head = xcd*4 + slot&3,
// qx = slot>>2; block handles q-tile pair {qx, 15-qx} (17 KV-128 iters, balanced).
// 2-deep counted-vmcnt pipeline, two barriers/iter, 64KB LDS -> 2 blocks/CU.
// Softmax in exp2 domain; cross-half exchange via __shfl_xor (verified form).
__global__ __launch_bounds__(512, 4) void attn_kernel(
    const ushort* __restrict__ qh, const ushort* __restrict__ kh,
    const ushort* __restrict__ vhT, ushort* __restrict__ yb)
{
    __shared__ __align__(16) char smem[65536];
    // buf b in {0,1}: K @ b*32768 (16KB), V^T @ b*32768+16384 (16KB)
    // merge scratch (36,864B) aliased @ 0 (bufs dead at merge time)
    const int tid = threadIdx.x;
    const int lane = tid & 63, wid = tid >> 6;
    const int l31 = lane & 31;
    const int hi  = lane >> 5;
    const int group = wid >> 2;          // 0 = even KV-64 half, 1 = odd
    const int wq    = wid & 3;
    const int subkv = group * 64;
    const int id = blockIdx.x;
    const int bh = (id & 7) * 4 + ((id >> 3) & 3);   // 4 heads per XCD slot-group
    const int qx = id >> 5;                           // 0..7
    const size_t base = (size_t)bh * 2048 * 64;
    const int b_ = bh >> 4, h_ = bh & 15;
    float* oml = (float*)smem;

    auto stageK = [&](int t, int b) {
        char* Ks = smem + b * 32768;
        #pragma unroll
        for (int it = 0; it < 2; ++it) {
            int c = it * 512 + tid;
            int row = c >> 3, inner = c & 7;
            async16((const char*)kh + (base + (size_t)(t * 128 + row) * 64) * 2 + ((inner ^ (row & 7)) * 16),
                    Ks + c * 16);
        }
    };
    auto stageV = [&](int t, int b) {
        char* Vs = smem + b * 32768 + 16384;
        #pragma unroll
        for (int it = 0; it < 2; ++it) {
            int c = it * 512 + tid;
            int row = c >> 4, inner = c & 15;   // row = d
            async16((const char*)vhT + (base + (size_t)row * 2048 + (size_t)t * 128) * 2 + ((inner ^ (row & 15)) * 16),
                    Vs + c * 16);
        }
    };

    for (int p = 0; p < 2; ++p) {
        const int qt  = (p == 0) ? qx : 15 - qx;
        const int qrw = qt * 128 + wq * 32;

        // hoist Q fragments (pre-scaled by 0.125*log2e at projection)
        bf16x8 qf[4];
        #pragma unroll
        for (int ks = 0; ks < 4; ++ks)
            qf[ks] = *(const bf16x8*)((const char*)qh + (base + (size_t)(qrw + l31) * 64) * 2 + ks * 32 + hi * 16);

        f32x16 o[2];
        #pragma unroll
        for (int r = 0; r < 16; ++r) { o[0][r] = 0.f; o[1][r] = 0.f; }
        float m_run = -1e30f, l_run = 0.f;

        stageK(0, 0); stageV(0, 0);

        for (int t = 0; t <= qt; ++t) {
            const bool more = (t + 1 <= qt);
            if (more) { stageK(t + 1, (t + 1) & 1); stageV(t + 1, (t + 1) & 1); }
            PIPE_BARRIER(more);   // own t-loads done; all waves' t-loads done

            const int kv0 = t * 128 + subkv;
            if (kv0 <= qrw + 31) {
                const char* Ks = smem + (t & 1) * 32768;
                const char* Vs = Ks + 16384;

                // ---- QK^T (swapped): st[tt][r] over K rows subkv + tt*32 + l31
                f32x16 st[2];
                #pragma unroll
                for (int r = 0; r < 16; ++r) { st[0][r] = 0.f; st[1][r] = 0.f; }
                __builtin_amdgcn_s_setprio(1);
                #pragma unroll
                for (int tt = 0; tt < 2; ++tt)
                    #pragma unroll
                    for (int ks = 0; ks < 4; ++ks) {
                        int krow = subkv + tt * 32 + l31;
                        int byte = (krow * 128 + ks * 32 + hi * 16) ^ ((krow & 7) << 4);
                        bf16x8 kf = *(const bf16x8*)(Ks + byte);
                        st[tt] = mfma32(kf, qf[ks], st[tt]);
                    }
                __builtin_amdgcn_s_setprio(0);

                // ---- causal mask (diagonal tiles only)
                if (kv0 + 63 > qrw) {
                    #pragma unroll
                    for (int tt = 0; tt < 2; ++tt)
                        #pragma unroll
                        for (int r = 0; r < 16; ++r) {
                            int kv = kv0 + tt * 32 + (r & 3) + 8 * (r >> 2) + 4 * hi;
                            if (kv > qrw + l31) st[tt][r] = -1e30f;
                        }
                }

                // ---- row max (lane-local + cross-half)
                float mx = st[0][0];
                #pragma unroll
                for (int tt = 0; tt < 2; ++tt)
                    #pragma unroll
                    for (int r = 0; r < 16; ++r) mx = fmaxf(mx, st[tt][r]);
                mx = xhalf_max(mx);

                // ---- defer-max online softmax (T13, THR=8 in log2 units)
                if (!__all(mx - m_run <= 8.0f)) {
                    float mn = fmaxf(m_run, mx);
                    float corr = __builtin_amdgcn_exp2f(m_run - mn);
                    l_run *= corr;
                    m_run = mn;
                    #pragma unroll
                    for (int r = 0; r < 16; ++r) {
                        int qsrc = (r & 3) + 8 * (r >> 2) + 4 * hi;
                        float c2 = __shfl(corr, qsrc);
                        o[0][r] *= c2; o[1][r] *= c2;
                    }
                }

                float sum = 0.f;
                #pragma unroll
                for (int tt = 0; tt < 2; ++tt)
                    #pragma unroll
                    for (int r = 0; r < 16; ++r) {
                        float pw = __builtin_amdgcn_exp2f(st[tt][r] - m_run);
                        st[tt][r] = pw;
                        sum += pw;
                    }
                sum = xhalf_sum(sum);
                l_run += sum;

                // ---- pack P to bf16 words; exchange across halves (verified shfl_xor)
                unsigned Wd[2][8], Xw[2][8];
                #pragma unroll
                for (int tt = 0; tt < 2; ++tt)
                    #pragma unroll
                    for (int k = 0; k < 8; ++k) {
                        unsigned w;
                        asm("v_cvt_pk_bf16_f32 %0, %1, %2" : "=v"(w) : "v"(st[tt][2 * k]), "v"(st[tt][2 * k + 1]));
                        Wd[tt][k] = w;
                    }
                #pragma unroll
                for (int tt = 0; tt < 2; ++tt)
                    #pragma unroll
                    for (int k = 0; k < 8; ++k)
                        Xw[tt][k] = __shfl_xor((int)Wd[tt][k], 32);

                // ---- PV
                #pragma unroll
                for (int ks = 0; ks < 4; ++ks) {
                    const int t2 = ks >> 1, bse = (ks & 1) * 4;
                    unsigned w0 = hi ? Xw[t2][bse + 2] : Wd[t2][bse + 0];
                    unsigned w1 = hi ? Xw[t2][bse + 3] : Wd[t2][bse + 1];
                    unsigned w2 = hi ? Wd[t2][bse + 2] : Xw[t2][bse + 0];
                    unsigned w3 = hi ? Wd[t2][bse + 3] : Xw[t2][bse + 1];
                    unsigned pw4[4] = {w0, w1, w2, w3};
                    bf16x8 pf = *(const bf16x8*)pw4;
                    __builtin_amdgcn_s_setprio(1);
                    #pragma unroll
                    for (int dt = 0; dt < 2; ++dt) {
                        int vrow = dt * 32 + l31;
                        int colB = subkv * 2 + ks * 32 + hi * 16;
                        int byte = vrow * 256 + (colB ^ ((vrow & 15) << 4));
                        bf16x8 vf = *(const bf16x8*)(Vs + byte);
                        o[dt] = mfma32(pf, vf, o[dt]);
                    }
                    __builtin_amdgcn_s_setprio(0);
                }
            }
            END_BARRIER();   // all waves' reads of buf[t&1] done -> stage(t+2) may overwrite
        }

        // ---- merge the two KV halves (oml aliased over dead bufs), store q-tile
        if (group == 1) {
            float* pp = oml + (size_t)(wq * 64 + lane) * 36;
            #pragma unroll
            for (int r = 0; r < 16; ++r) { pp[r] = o[0][r]; pp[16 + r] = o[1][r]; }
            pp[32] = m_run; pp[33] = l_run;
        }
        __syncthreads();
        if (group == 0) {
            const float* pp = oml + (size_t)(wq * 64 + lane) * 36;
            float m1 = pp[32], l1 = pp[33];
            float mn = fmaxf(m_run, m1);
            float a0 = __builtin_amdgcn_exp2f(m_run - mn);
            float a1 = __builtin_amdgcn_exp2f(m1 - mn);
            float lt = l_run * a0 + l1 * a1;
            float invl = 1.0f / lt;
            #pragma unroll
            for (int r = 0; r < 16; ++r) {
                int qsrc = (r & 3) + 8 * (r >> 2) + 4 * hi;
                float f0 = __shfl(a0, qsrc);
                float f1 = __shfl(a1, qsrc);
                float iv = __shfl(invl, qsrc);
                float v0 = (o[0][r] * f0 + pp[r] * f1) * iv;
                float v1 = (o[1][r] * f0 + pp[16 + r] * f1) * iv;
                int q = qrw + qsrc;
                size_t rowoff = ((size_t)(b_ * 2048 + q)) * 1024 + h_ * 64;
                yb[rowoff + l31]      = f2bf(v0);
                yb[rowoff + 32 + l31] = f2bf(v1);
            }
        }
        __syncthreads();
    }
}

extern "C" void kernel_launch(void* const* d_in, const int* in_sizes, int n_in,
                              void* d_out, int out_size, void* d_ws, size_t ws_size,
                              hipStream_t stream)
{
    const size_t MD = 4096ull * 1024;
    const size_t WD = 1024ull * 1024;
    ushort* ws  = (ushort*)d_ws;
    ushort* Qb  = ws;
    ushort* Kb  = Qb + MD;
    ushort* Vb  = Kb + MD;
    ushort* qhb = Vb + MD;
    ushort* khb = qhb + MD;
    ushort* vhT = khb + MD;
    ushort* WQb = vhT + MD;
    ushort* WKb = WQb + WD;
    ushort* WVb = WKb + WD;
    ushort* Wfb = WVb + WD;
    ushort* yb  = Qb;   // alias: Qb dead after QKV projection

    cvt7_kernel<<<dim3(4096, 7), 256, 0, stream>>>(
        (const float*)d_in[0], (const float*)d_in[1], (const float*)d_in[2],
        (const float*)d_in[3], (const float*)d_in[4], (const float*)d_in[5],
        (const float*)d_in[6],
        Qb, Kb, Vb, WQb, WKb, WVb, Wfb);

    gemm_qkv<<<dim3(96, 8), 256, 0, stream>>>(Qb, Kb, Vb, WQb, WKb, WVb, qhb, khb, vhT);
    attn_kernel<<<256, 512, 0, stream>>>(qhb, khb, vhT, yb);
    gemm_fc<<<dim3(32, 8), 256, 0, stream>>>(yb, Wfb, (float*)d_out, (const float*)d_in[7]);
}

// Round 9
// 108.625 us; speedup vs baseline: 1.1212x; 1.0754x over previous
//
#include <hip/hip_runtime.h>

typedef __attribute__((ext_vector_type(8))) short bf16x8;
typedef __attribute__((ext_vector_type(4))) float f32x4;
typedef __attribute__((ext_vector_type(16))) float f32x16;

__device__ __forceinline__ ushort f2bf(float f) {
    union { float f; unsigned u; } x; x.f = f;
    unsigned r = x.u + 0x7fffu + ((x.u >> 16) & 1u);
    return (ushort)(r >> 16);
}

__device__ __forceinline__ void async16(const void* g, void* l) {
    __builtin_amdgcn_global_load_lds(
        (const __attribute__((address_space(1))) void*)g,
        (__attribute__((address_space(3))) void*)l, 16, 0, 0);
}

__device__ __forceinline__ f32x4 mfma16(bf16x8 a, bf16x8 b, f32x4 c) {
    return __builtin_amdgcn_mfma_f32_16x16x32_bf16(a, b, c, 0, 0, 0);
}
__device__ __forceinline__ f32x16 mfma32(bf16x8 a, bf16x8 b, f32x16 c) {
    return __builtin_amdgcn_mfma_f32_32x32x16_bf16(a, b, c, 0, 0, 0);
}

__device__ __forceinline__ f32x4 zero4() { f32x4 z = {0.f, 0.f, 0.f, 0.f}; return z; }

// cross-half (lane vs lane^32) reduce — VERIFIED shfl_xor form (R3-R5/R8).
// NOTE: inline-asm v_permlane32_swap_b32 failed correctness in both operand
// orders (R6/R7, absmax ~4) — do not reintroduce.
__device__ __forceinline__ float xhalf_max(float v) {
    return fmaxf(v, __shfl_xor(v, 32));
}
__device__ __forceinline__ float xhalf_sum(float v) {
    return v + __shfl_xor(v, 32);
}

#define PIPE_BARRIER(cond_more)                                          \
    do {                                                                 \
        if (cond_more) asm volatile("s_waitcnt vmcnt(4)" ::: "memory");  \
        else           asm volatile("s_waitcnt vmcnt(0)" ::: "memory");  \
        asm volatile("s_waitcnt lgkmcnt(0)" ::: "memory");               \
        __builtin_amdgcn_sched_barrier(0);                               \
        __builtin_amdgcn_s_barrier();                                    \
        __builtin_amdgcn_sched_barrier(0);                               \
    } while (0)

#define END_BARRIER()                                                    \
    do {                                                                 \
        asm volatile("s_waitcnt lgkmcnt(0)" ::: "memory");               \
        __builtin_amdgcn_sched_barrier(0);                               \
        __builtin_amdgcn_s_barrier();                                    \
        __builtin_amdgcn_sched_barrier(0);                               \
    } while (0)

// -------- fused fp32 -> bf16 conversion for all 7 tensors, one launch --------
__global__ void cvt7_kernel(
    const float* __restrict__ s0, const float* __restrict__ s1, const float* __restrict__ s2,
    const float* __restrict__ s3, const float* __restrict__ s4, const float* __restrict__ s5,
    const float* __restrict__ s6,
    ushort* __restrict__ d0, ushort* __restrict__ d1, ushort* __restrict__ d2,
    ushort* __restrict__ d3, ushort* __restrict__ d4, ushort* __restrict__ d5,
    ushort* __restrict__ d6)
{
    int y = blockIdx.y;
    const float* s; ushort* d; int n4;
    if      (y == 0) { s = s0; d = d0; n4 = 1048576; }
    else if (y == 1) { s = s1; d = d1; n4 = 1048576; }
    else if (y == 2) { s = s2; d = d2; n4 = 1048576; }
    else if (y == 3) { s = s3; d = d3; n4 = 262144; }
    else if (y == 4) { s = s4; d = d4; n4 = 262144; }
    else if (y == 5) { s = s5; d = d5; n4 = 262144; }
    else             { s = s6; d = d6; n4 = 262144; }
    int i = blockIdx.x * 256 + threadIdx.x;
    if (i >= n4) return;
    float4 v = ((const float4*)s)[i];
    ushort4 o;
    o.x = f2bf(v.x); o.y = f2bf(v.y); o.z = f2bf(v.z); o.w = f2bf(v.w);
    ((ushort4*)d)[i] = o;
}

// -------- shared GEMM core: 128x128 tile, BK=32, 3-deep counted-vmcnt pipeline --------
template<bool SWAP>
__device__ __forceinline__ void gemm_core(
    const ushort* __restrict__ A, const ushort* __restrict__ W,
    char* smem, int bm, int bn, int tid, f32x4 acc[4][4])
{
    const int lane = tid & 63;
    const int wid  = tid >> 6;
    const int wr = wid >> 1, wc = wid & 1;
    const int l15 = lane & 15, g = lane >> 4;

    auto stage = [&](int kt) {
        char* As = smem + (kt % 3) * 16384;
        char* Bs = As + 8192;
        #pragma unroll
        for (int it = 0; it < 2; ++it) {
            int c = it * 256 + tid;
            int row = c >> 2, inner = c & 3;
            int srcoff = (inner ^ (row & 3)) * 16;
            async16((const char*)A + (size_t)(bm * 128 + row) * 2048 + kt * 64 + srcoff, As + c * 16);
            async16((const char*)W + (size_t)(bn * 128 + row) * 2048 + kt * 64 + srcoff, Bs + c * 16);
        }
    };

    stage(0);
    stage(1);

    for (int kt = 0; kt < 32; ++kt) {
        PIPE_BARRIER(kt < 31);
        if (kt < 30) stage(kt + 2);

        const char* As = smem + (kt % 3) * 16384;
        const char* Bs = As + 8192;
        bf16x8 af[4], bfr[4];
        #pragma unroll
        for (int mt = 0; mt < 4; ++mt) {
            int row = wr * 64 + mt * 16 + l15;
            af[mt] = *(const bf16x8*)(As + ((row * 64 + g * 16) ^ ((row & 3) << 4)));
        }
        #pragma unroll
        for (int nt = 0; nt < 4; ++nt) {
            int row = wc * 64 + nt * 16 + l15;
            bfr[nt] = *(const bf16x8*)(Bs + ((row * 64 + g * 16) ^ ((row & 3) << 4)));
        }
        __builtin_amdgcn_s_setprio(1);
        #pragma unroll
        for (int mt = 0; mt < 4; ++mt)
            #pragma unroll
            for (int nt = 0; nt < 4; ++nt) {
                if (SWAP) acc[mt][nt] = mfma16(bfr[nt], af[mt], acc[mt][nt]);
                else      acc[mt][nt] = mfma16(af[mt], bfr[nt], acc[mt][nt]);
            }
        __builtin_amdgcn_s_setprio(0);
    }
}

// -------- merged QKV projection: grid (96, 8), z = x%3 --------
// Q scaled by 0.125*log2(e) (exp2-domain softmax downstream).
__global__ __launch_bounds__(256, 2) void gemm_qkv(
    const ushort* __restrict__ Qb, const ushort* __restrict__ Kb, const ushort* __restrict__ Vb,
    const ushort* __restrict__ WQ, const ushort* __restrict__ WK, const ushort* __restrict__ WV,
    ushort* __restrict__ qhb, ushort* __restrict__ khb, ushort* __restrict__ vhT)
{
    __shared__ __align__(16) char smem[49152];
    const int tid = threadIdx.x;
    const int z  = blockIdx.x % 3;
    const int bm = blockIdx.x / 3;
    const int bn = blockIdx.y;
    const int lane = tid & 63;
    const int wid  = tid >> 6;
    const int wr = wid >> 1, wc = wid & 1;
    const int l15 = lane & 15, g = lane >> 4;

    const ushort* A  = (z == 0) ? Qb : (z == 1) ? Kb : Vb;
    const ushort* Wm = (z == 0) ? WQ : (z == 1) ? WK : WV;

    f32x4 acc[4][4];
    #pragma unroll
    for (int i = 0; i < 4; ++i)
        #pragma unroll
        for (int j = 0; j < 4; ++j) acc[i][j] = zero4();

    if (z == 2) {
        gemm_core<true>(A, Wm, smem, bm, bn, tid, acc);
        #pragma unroll
        for (int mt = 0; mt < 4; ++mt)
            #pragma unroll
            for (int nt = 0; nt < 4; ++nt)
                #pragma unroll
                for (int j = 0; j < 4; ++j) {
                    int n = bn * 128 + wc * 64 + nt * 16 + g * 4 + j;
                    int m = bm * 128 + wr * 64 + mt * 16 + l15;
                    int b = m >> 11, s = m & 2047, h = (n >> 6) & 15, d = n & 63;
                    vhT[(((size_t)(b * 16 + h)) * 64 + d) * 2048 + s] = f2bf(acc[mt][nt][j]);
                }
    } else {
        gemm_core<false>(A, Wm, smem, bm, bn, tid, acc);
        const float scale = (z == 0) ? 0.18033688011112042f : 1.0f;  // 0.125 * log2(e)
        ushort* outb = (z == 0) ? qhb : khb;
        #pragma unroll
        for (int mt = 0; mt < 4; ++mt)
            #pragma unroll
            for (int nt = 0; nt < 4; ++nt)
                #pragma unroll
                for (int j = 0; j < 4; ++j) {
                    int m = bm * 128 + wr * 64 + mt * 16 + g * 4 + j;
                    int n = bn * 128 + wc * 64 + nt * 16 + l15;
                    int b = m >> 11, s = m & 2047, h = n >> 6, d = n & 63;
                    outb[(((size_t)(b * 16 + h)) * 2048 + s) * 64 + d] = f2bf(acc[mt][nt][j] * scale);
                }
    }
}

// -------- final GEMM: out = A @ W^T + bias (fp32 out) --------
__global__ __launch_bounds__(256, 2) void gemm_fc(
    const ushort* __restrict__ A, const ushort* __restrict__ W,
    float* __restrict__ outf, const float* __restrict__ bias)
{
    __shared__ __align__(16) char smem[49152];
    const int tid = threadIdx.x;
    const int lane = tid & 63;
    const int wid  = tid >> 6;
    const int wr = wid >> 1, wc = wid & 1;
    const int l15 = lane & 15, g = lane >> 4;

    f32x4 acc[4][4];
    #pragma unroll
    for (int i = 0; i < 4; ++i)
        #pragma unroll
        for (int j = 0; j < 4; ++j) acc[i][j] = zero4();

    gemm_core<false>(A, W, smem, blockIdx.x, blockIdx.y, tid, acc);

    #pragma unroll
    for (int mt = 0; mt < 4; ++mt)
        #pragma unroll
        for (int nt = 0; nt < 4; ++nt)
            #pragma unroll
            for (int j = 0; j < 4; ++j) {
                int m = blockIdx.x * 128 + wr * 64 + mt * 16 + g * 4 + j;
                int n = blockIdx.y * 128 + wc * 64 + nt * 16 + l15;
                outf[(size_t)m * 1024 + n] = acc[mt][nt][j] + bias[n];
            }
}

// -------- causal flash attention --------
// grid 256 1-D. block 512 = 8 waves. XCD-aware decode. q-tile pair {qx, 15-qx}
// (17 KV-128 iters, balanced). 2-deep counted-vmcnt pipeline.
// R9: batched K-frag reads (one lgkm wait), V-frag reads hoisted above softmax
// (latency hidden under softmax VALU), tree reductions for row max/sum.
__global__ __launch_bounds__(512) void attn_kernel(
    const ushort* __restrict__ qh, const ushort* __restrict__ kh,
    const ushort* __restrict__ vhT, ushort* __restrict__ yb)
{
    __shared__ __align__(16) char smem[65536];
    // buf b in {0,1}: K @ b*32768 (16KB), V^T @ b*32768+16384 (16KB)
    // merge scratch (36,864B) aliased @ 0 (bufs dead at merge time)
    const int tid = threadIdx.x;
    const int lane = tid & 63, wid = tid >> 6;
    const int l31 = lane & 31;
    const int hi  = lane >> 5;
    const int group = wid >> 2;          // 0 = even KV-64 half, 1 = odd
    const int wq    = wid & 3;
    const int subkv = group * 64;
    const int id = blockIdx.x;
    const int bh = (id & 7) * 4 + ((id >> 3) & 3);   // 4 heads per XCD slot-group
    const int qx = id >> 5;                           // 0..7
    const size_t base = (size_t)bh * 2048 * 64;
    const int b_ = bh >> 4, h_ = bh & 15;
    float* oml = (float*)smem;

    auto stageK = [&](int t, int b) {
        char* Ks = smem + b * 32768;
        #pragma unroll
        for (int it = 0; it < 2; ++it) {
            int c = it * 512 + tid;
            int row = c >> 3, inner = c & 7;
            async16((const char*)kh + (base + (size_t)(t * 128 + row) * 64) * 2 + ((inner ^ (row & 7)) * 16),
                    Ks + c * 16);
        }
    };
    auto stageV = [&](int t, int b) {
        char* Vs = smem + b * 32768 + 16384;
        #pragma unroll
        for (int it = 0; it < 2; ++it) {
            int c = it * 512 + tid;
            int row = c >> 4, inner = c & 15;   // row = d
            async16((const char*)vhT + (base + (size_t)row * 2048 + (size_t)t * 128) * 2 + ((inner ^ (row & 15)) * 16),
                    Vs + c * 16);
        }
    };

    for (int p = 0; p < 2; ++p) {
        const int qt  = (p == 0) ? qx : 15 - qx;
        const int qrw = qt * 128 + wq * 32;

        // hoist Q fragments (pre-scaled by 0.125*log2e at projection)
        bf16x8 qf[4];
        #pragma unroll
        for (int ks = 0; ks < 4; ++ks)
            qf[ks] = *(const bf16x8*)((const char*)qh + (base + (size_t)(qrw + l31) * 64) * 2 + ks * 32 + hi * 16);

        f32x16 o[2];
        #pragma unroll
        for (int r = 0; r < 16; ++r) { o[0][r] = 0.f; o[1][r] = 0.f; }
        float m_run = -1e30f, l_run = 0.f;

        stageK(0, 0); stageV(0, 0);

        for (int t = 0; t <= qt; ++t) {
            const bool more = (t + 1 <= qt);
            if (more) { stageK(t + 1, (t + 1) & 1); stageV(t + 1, (t + 1) & 1); }
            PIPE_BARRIER(more);   // own t-loads done; all waves' t-loads done

            const int kv0 = t * 128 + subkv;
            if (kv0 <= qrw + 31) {
                const char* Ks = smem + (t & 1) * 32768;
                const char* Vs = Ks + 16384;

                // ---- batch ALL K-fragment reads (8 x b128, one lgkm wait at use)
                bf16x8 kf[2][4];
                #pragma unroll
                for (int tt = 0; tt < 2; ++tt)
                    #pragma unroll
                    for (int ks = 0; ks < 4; ++ks) {
                        int krow = subkv + tt * 32 + l31;
                        int byte = (krow * 128 + ks * 32 + hi * 16) ^ ((krow & 7) << 4);
                        kf[tt][ks] = *(const bf16x8*)(Ks + byte);
                    }

                // ---- QK^T (swapped): st[tt][r] over K rows subkv + tt*32 + l31
                f32x16 st[2];
                #pragma unroll
                for (int r = 0; r < 16; ++r) { st[0][r] = 0.f; st[1][r] = 0.f; }
                __builtin_amdgcn_s_setprio(1);
                #pragma unroll
                for (int tt = 0; tt < 2; ++tt)
                    #pragma unroll
                    for (int ks = 0; ks < 4; ++ks)
                        st[tt] = mfma32(kf[tt][ks], qf[ks], st[tt]);
                __builtin_amdgcn_s_setprio(0);

                // ---- hoist ALL V-fragment reads; softmax VALU below hides latency
                bf16x8 vf[4][2];
                #pragma unroll
                for (int ks = 0; ks < 4; ++ks)
                    #pragma unroll
                    for (int dt = 0; dt < 2; ++dt) {
                        int vrow = dt * 32 + l31;
                        int colB = subkv * 2 + ks * 32 + hi * 16;
                        int byte = vrow * 256 + (colB ^ ((vrow & 15) << 4));
                        vf[ks][dt] = *(const bf16x8*)(Vs + byte);
                    }

                // ---- causal mask (diagonal tiles only)
                if (kv0 + 63 > qrw) {
                    #pragma unroll
                    for (int tt = 0; tt < 2; ++tt)
                        #pragma unroll
                        for (int r = 0; r < 16; ++r) {
                            int kv = kv0 + tt * 32 + (r & 3) + 8 * (r >> 2) + 4 * hi;
                            if (kv > qrw + l31) st[tt][r] = -1e30f;
                        }
                }

                // ---- row max: tree reduction (depth 5) + cross-half
                float mx;
                {
                    float t0[8];
                    #pragma unroll
                    for (int r = 0; r < 8; ++r)
                        t0[r] = fmaxf(fmaxf(st[0][r], st[0][r + 8]),
                                      fmaxf(st[1][r], st[1][r + 8]));
                    float t1[4];
                    #pragma unroll
                    for (int r = 0; r < 4; ++r) t1[r] = fmaxf(t0[r], t0[r + 4]);
                    float t2a = fmaxf(t1[0], t1[2]), t2b = fmaxf(t1[1], t1[3]);
                    mx = fmaxf(t2a, t2b);
                }
                mx = xhalf_max(mx);

                // ---- defer-max online softmax (T13, THR=8 in log2 units)
                if (!__all(mx - m_run <= 8.0f)) {
                    float mn = fmaxf(m_run, mx);
                    float corr = __builtin_amdgcn_exp2f(m_run - mn);
                    l_run *= corr;
                    m_run = mn;
                    #pragma unroll
                    for (int r = 0; r < 16; ++r) {
                        int qsrc = (r & 3) + 8 * (r >> 2) + 4 * hi;
                        float c2 = __shfl(corr, qsrc);
                        o[0][r] *= c2; o[1][r] *= c2;
                    }
                }

                // ---- exp2 + tree sum
                #pragma unroll
                for (int tt = 0; tt < 2; ++tt)
                    #pragma unroll
                    for (int r = 0; r < 16; ++r)
                        st[tt][r] = __builtin_amdgcn_exp2f(st[tt][r] - m_run);
                float sum;
                {
                    float s0[8];
                    #pragma unroll
                    for (int r = 0; r < 8; ++r)
                        s0[r] = (st[0][r] + st[0][r + 8]) + (st[1][r] + st[1][r + 8]);
                    float s1[4];
                    #pragma unroll
                    for (int r = 0; r < 4; ++r) s1[r] = s0[r] + s0[r + 4];
                    sum = (s1[0] + s1[2]) + (s1[1] + s1[3]);
                }
                sum = xhalf_sum(sum);
                l_run += sum;

                // ---- pack P to bf16 words; exchange across halves (verified shfl_xor)
                unsigned Wd[2][8], Xw[2][8];
                #pragma unroll
                for (int tt = 0; tt < 2; ++tt)
                    #pragma unroll
                    for (int k = 0; k < 8; ++k) {
                        unsigned w;
                        asm("v_cvt_pk_bf16_f32 %0, %1, %2" : "=v"(w) : "v"(st[tt][2 * k]), "v"(st[tt][2 * k + 1]));
                        Wd[tt][k] = w;
                    }
                #pragma unroll
                for (int tt = 0; tt < 2; ++tt)
                    #pragma unroll
                    for (int k = 0; k < 8; ++k)
                        Xw[tt][k] = __shfl_xor((int)Wd[tt][k], 32);

                // ---- PV (V already in registers)
                #pragma unroll
                for (int ks = 0; ks < 4; ++ks) {
                    const int t2 = ks >> 1, bse = (ks & 1) * 4;
                    unsigned w0 = hi ? Xw[t2][bse + 2] : Wd[t2][bse + 0];
                    unsigned w1 = hi ? Xw[t2][bse + 3] : Wd[t2][bse + 1];
                    unsigned w2 = hi ? Wd[t2][bse + 2] : Xw[t2][bse + 0];
                    unsigned w3 = hi ? Wd[t2][bse + 3] : Xw[t2][bse + 1];
                    unsigned pw4[4] = {w0, w1, w2, w3};
                    bf16x8 pf = *(const bf16x8*)pw4;
                    __builtin_amdgcn_s_setprio(1);
                    #pragma unroll
                    for (int dt = 0; dt < 2; ++dt)
                        o[dt] = mfma32(pf, vf[ks][dt], o[dt]);
                    __builtin_amdgcn_s_setprio(0);
                }
            }
            END_BARRIER();   // all waves' reads of buf[t&1] done -> stage(t+2) may overwrite
        }

        // ---- merge the two KV halves (oml aliased over dead bufs), store q-tile
        if (group == 1) {
            float* pp = oml + (size_t)(wq * 64 + lane) * 36;
            #pragma unroll
            for (int r = 0; r < 16; ++r) { pp[r] = o[0][r]; pp[16 + r] = o[1][r]; }
            pp[32] = m_run; pp[33] = l_run;
        }
        __syncthreads();
        if (group == 0) {
            const float* pp = oml + (size_t)(wq * 64 + lane) * 36;
            float m1 = pp[32], l1 = pp[33];
            float mn = fmaxf(m_run, m1);
            float a0 = __builtin_amdgcn_exp2f(m_run - mn);
            float a1 = __builtin_amdgcn_exp2f(m1 - mn);
            float lt = l_run * a0 + l1 * a1;
            float invl = 1.0f / lt;
            #pragma unroll
            for (int r = 0; r < 16; ++r) {
                int qsrc = (r & 3) + 8 * (r >> 2) + 4 * hi;
                float f0 = __shfl(a0, qsrc);
                float f1 = __shfl(a1, qsrc);
                float iv = __shfl(invl, qsrc);
                float v0 = (o[0][r] * f0 + pp[r] * f1) * iv;
                float v1 = (o[1][r] * f0 + pp[16 + r] * f1) * iv;
                int q = qrw + qsrc;
                size_t rowoff = ((size_t)(b_ * 2048 + q)) * 1024 + h_ * 64;
                yb[rowoff + l31]      = f2bf(v0);
                yb[rowoff + 32 + l31] = f2bf(v1);
            }
        }
        __syncthreads();
    }
}

extern "C" void kernel_launch(void* const* d_in, const int* in_sizes, int n_in,
                              void* d_out, int out_size, void* d_ws, size_t ws_size,
                              hipStream_t stream)
{
    const size_t MD = 4096ull * 1024;
    const size_t WD = 1024ull * 1024;
    ushort* ws  = (ushort*)d_ws;
    ushort* Qb  = ws;
    ushort* Kb  = Qb + MD;
    ushort* Vb  = Kb + MD;
    ushort* qhb = Vb + MD;
    ushort* khb = qhb + MD;
    ushort* vhT = khb + MD;
    ushort* WQb = vhT + MD;
    ushort* WKb = WQb + WD;
    ushort* WVb = WKb + WD;
    ushort* Wfb = WVb + WD;
    ushort* yb  = Qb;   // alias: Qb dead after QKV projection

    cvt7_kernel<<<dim3(4096, 7), 256, 0, stream>>>(
        (const float*)d_in[0], (const float*)d_in[1], (const float*)d_in[2],
        (const float*)d_in[3], (const float*)d_in[4], (const float*)d_in[5],
        (const float*)d_in[6],
        Qb, Kb, Vb, WQb, WKb, WVb, Wfb);

    gemm_qkv<<<dim3(96, 8), 256, 0, stream>>>(Qb, Kb, Vb, WQb, WKb, WVb, qhb, khb, vhT);
    attn_kernel<<<256, 512, 0, stream>>>(qhb, khb, vhT, yb);
    gemm_fc<<<dim3(32, 8), 256, 0, stream>>>(yb, Wfb, (float*)d_out, (const float*)d_in[7]);
}